// Round 11
// baseline (504.487 us; speedup 1.0000x reference)
//
#include <hip/hip_runtime.h>
#include <hip/hip_cooperative_groups.h>
#include <math.h>

namespace cg = cooperative_groups;

#define NODES   62
#define DEG     16
#define EPN     17                  // edges per node incl. self-loop
#define EPG     (NODES*EPN)         // 1054
#define NGRAPH  4096
#define NTOT    (NGRAPH*NODES)      // 253952
#define FIN     32
#define HIDC    64
#define XS      72                  // bf16 row stride (144B -> b128 aligned, banks rotate)
#define WS      40                  // bf16 row stride for phase-a operand tiles
#define GRIDB   768                 // MAX grid (3/CU x 256 CU); actual grid from occupancy

typedef __attribute__((ext_vector_type(8))) short bf16x8;   // MFMA A/B frag
typedef __attribute__((ext_vector_type(4))) float f32x4;    // MFMA C/D frag

__device__ __forceinline__ unsigned short bf16r(float f) {   // f32 -> bf16 RNE
    unsigned int u = __float_as_uint(f);
    u += 0x7fffu + ((u >> 16) & 1u);
    return (unsigned short)(u >> 16);
}
__device__ __forceinline__ unsigned int pk2(float a, float b) {
    return (unsigned int)bf16r(a) | ((unsigned int)bf16r(b) << 16);
}
__device__ __forceinline__ float blo(unsigned int d) { return __uint_as_float(d << 16); }
__device__ __forceinline__ float bhi(unsigned int d) { return __uint_as_float(d & 0xffff0000u); }
__device__ __forceinline__ float lrelu(float z) { return fmaxf(z, 0.2f*z); }

// ---------------------------------------------------------------------------
// ONE cooperative kernel: phase1 = GATv2 L1 (MFMA) for all graphs (grid-stride)
// + register BN partials; grid.sync; block0 folds BN into L2 weights; grid.sync;
// phase3 = GATv2 L2 + GELU. Grid size chosen at launch from the runtime's own
// occupancy calculation (R10 lesson: fixed 768 was rejected -> silent no-op).
// ---------------------------------------------------------------------------
__global__ __launch_bounds__(256, 3) void fused_kernel(
    const float* __restrict__ x, const int* __restrict__ esrc,
    const float* __restrict__ Wl, const float* __restrict__ bl,
    const float* __restrict__ Wr, const float* __restrict__ br,
    const float* __restrict__ att, const float* __restrict__ bias,
    const float* __restrict__ gamma, const float* __restrict__ beta,
    const float* __restrict__ Wl2, const float* __restrict__ bl2,
    const float* __restrict__ Wr2, const float* __restrict__ br2,
    const float* __restrict__ att2, const float* __restrict__ bias2,
    unsigned short* __restrict__ hb, float* __restrict__ part,
    float* __restrict__ fw, float* __restrict__ out)
{
    // R0 overlay: {xbf|wlT|wrT} staging -> {xlt|Pb} per graph -> fold scratch
    __shared__ __align__(16) unsigned char R0[18432];
    __shared__ __align__(16) unsigned char U1[1152];   // {blL,brL,attL} -> {fwL,xl2s,xr2s}
    __shared__ __align__(16) unsigned char U2[2112];   // eS -> srcs2
    __shared__ float aw[EPG];                          // 4216 B
    __shared__ __align__(16) unsigned short xlb[64*XS];// 9216 B
    __shared__ __align__(16) unsigned short xrb[64*XS];// 9216 B
    __shared__ float redS[4][64];                      // 1024 B
    __shared__ float redQ[4][64];                      // 1024 B  (total ~46.4 KB)

    unsigned short* xbf = (unsigned short*)R0;              // [64][WS]
    unsigned short* wlT = (unsigned short*)(R0 + 5120);     // [64][WS] (one-time)
    unsigned short* wrT = (unsigned short*)(R0 + 10240);    // [64][WS] (one-time)
    unsigned short* xlt = (unsigned short*)R0;              // [64][XS] after S2
    unsigned short* Pb  = (unsigned short*)(R0 + 9216);     // [64][XS] after S5
    float*        blL  = (float*)U1;
    float*        brL  = (float*)(U1 + 256);
    unsigned int* attL = (unsigned int*)(U1 + 512);
    unsigned short* eS = (unsigned short*)U2;

    const int tid = threadIdx.x;
    const int wv = tid >> 6, l = tid & 63, r16 = l & 15, kg = l >> 4;

    // ---- one-time staging: weights, biases, att ----
    for (int i = tid; i < FIN*HIDC; i += 256) {
        const int k = i >> 6, c = i & 63;
        wlT[c*WS + k] = bf16r(Wl[i]);
        wrT[c*WS + k] = bf16r(Wr[i]);
    }
    if (tid < HIDC) { blL[tid] = bl[tid]; brL[tid] = br[tid]; }
    if (tid < 32) attL[tid] = pk2(att[2*tid], att[2*tid+1]);
    __syncthreads();

    // loop-invariant registers: B-frags + packed att
    bf16x8 bLreg[4], bRreg[4];
#pragma unroll
    for (int ct = 0; ct < 4; ++ct) {
        bLreg[ct] = *(const bf16x8*)(wlT + (ct*16 + r16)*WS + kg*8);
        bRreg[ct] = *(const bf16x8*)(wrT + (ct*16 + r16)*WS + kg*8);
    }
    uint4 apr[8];
#pragma unroll
    for (int q = 0; q < 8; ++q) apr[q] = ((const uint4*)attL)[q];

    float bns[16], bnq[16];                 // BN partials (c = ct*16+kg*4+j)
#pragma unroll
    for (int t = 0; t < 16; ++t) { bns[t] = 0.f; bnq[t] = 0.f; }

    // ================= phase 1: GATv2 layer 1 =================
    for (int g = blockIdx.x; g < NGRAPH; g += gridDim.x) {
        const int nbase = g * NODES;
        __syncthreads();                            // prior iter xlt/Pb/eS reads done
        {   // stage x -> bf16 (rows 62,63 zeroed)
            const float2* xg = (const float2*)(x + (size_t)nbase * FIN);
            for (int i = tid; i < 64*16; i += 256) {
                const int n = i >> 4, c2 = i & 15;
                unsigned int pkv = 0u;
                if (n < NODES) { const float2 v = xg[i]; pkv = pk2(v.x, v.y); }
                ((unsigned int*)xbf)[n*(WS/2) + c2] = pkv;
            }
        }
        const int* eg = esrc + (size_t)nbase * DEG;
        for (int i = tid; i < EPG; i += 256) {
            const unsigned int d = ((unsigned int)i * 61681u) >> 20;   // i/17 exact
            const int j = i - (int)d * EPN;
            const int s = (j < DEG) ? (eg[(int)d*DEG + j] - nbase) : (int)d;
            eS[i] = (unsigned short)s;
        }
        __syncthreads();                            // S1

        // phase-a MFMA (B from registers)
        f32x4 aL[4], aR[4];
        {
            const bf16x8 afr = *(const bf16x8*)(xbf + (wv*16 + r16)*WS + kg*8);
            const f32x4 zz = {0.f, 0.f, 0.f, 0.f};
#pragma unroll
            for (int ct = 0; ct < 4; ++ct) {
                aL[ct] = __builtin_amdgcn_mfma_f32_16x16x32_bf16(afr, bLreg[ct], zz, 0, 0, 0);
                aR[ct] = __builtin_amdgcn_mfma_f32_16x16x32_bf16(afr, bRreg[ct], zz, 0, 0, 0);
            }
        }
        __syncthreads();                            // S2 (xbf dead)

        // epilogue: D[row=wv*16+kg*4+j][col=ct*16+r16] -> xlb, xlt, xrb
#pragma unroll
        for (int ct = 0; ct < 4; ++ct) {
            const int col = ct*16 + r16;
            const float bLc = blL[col], bRc = brL[col];
#pragma unroll
            for (int j = 0; j < 4; ++j) {
                const int row = wv*16 + kg*4 + j;
                const unsigned short xv = bf16r(aL[ct][j] + bLc);
                xlb[row*XS + col] = xv;
                xlt[col*XS + row] = xv;
                xrb[row*XS + col] = bf16r(aR[ct][j] + bRc);
            }
        }
        __syncthreads();                            // S3

        // alpha: one lane per edge, serial over 64 channels
        for (int i = tid; i < EPG; i += 256) {
            const unsigned int d = ((unsigned int)i * 61681u) >> 20;
            const int s = eS[i];
            const uint4* lp = (const uint4*)(xlb + s*XS);
            const uint4* rp = (const uint4*)(xrb + (int)d*XS);
            float acc = 0.f;
#pragma unroll
            for (int q = 0; q < 8; ++q) {
                const uint4 lv = lp[q];
                const uint4 rv = rp[q];
                const uint4 ap = apr[q];
                float z;
                z = blo(lv.x)+blo(rv.x); acc += blo(ap.x) * lrelu(z);
                z = bhi(lv.x)+bhi(rv.x); acc += bhi(ap.x) * lrelu(z);
                z = blo(lv.y)+blo(rv.y); acc += blo(ap.y) * lrelu(z);
                z = bhi(lv.y)+bhi(rv.y); acc += bhi(ap.y) * lrelu(z);
                z = blo(lv.z)+blo(rv.z); acc += blo(ap.z) * lrelu(z);
                z = bhi(lv.z)+bhi(rv.z); acc += bhi(ap.z) * lrelu(z);
                z = blo(lv.w)+blo(rv.w); acc += blo(ap.w) * lrelu(z);
                z = bhi(lv.w)+bhi(rv.w); acc += bhi(ap.w) * lrelu(z);
            }
            aw[i] = acc;
        }
        __syncthreads();                            // S4

        // softmax per node: 4-lane quads, edges split 4/4/4/5
        {
            const int node = tid >> 2, sub = tid & 3;
            if (node < NODES) {
                const int base = node*EPN + sub*4;
                float a0 = aw[base+0], a1 = aw[base+1];
                float a2 = aw[base+2], a3 = aw[base+3];
                const bool h5 = (sub == 3);
                float a4 = h5 ? aw[base+4] : -1e30f;
                float m = fmaxf(fmaxf(fmaxf(a0,a1), fmaxf(a2,a3)), a4);
                m = fmaxf(m, __shfl_xor(m,1));
                m = fmaxf(m, __shfl_xor(m,2));
                a0 = __expf(a0-m); a1 = __expf(a1-m); a2 = __expf(a2-m); a3 = __expf(a3-m);
                a4 = h5 ? __expf(a4-m) : 0.f;
                float ss = a0+a1+a2+a3+a4;
                ss += __shfl_xor(ss,1);
                ss += __shfl_xor(ss,2);
                const float inv = 1.f/(ss + 1e-16f);
                aw[base+0] = a0*inv; aw[base+1] = a1*inv;
                aw[base+2] = a2*inv; aw[base+3] = a3*inv;
                if (h5) aw[base+4] = a4*inv;
            }
        }
        __syncthreads();                            // S5

        // build dense P (bf16), f32 accumulation of duplicate edges
        {
            const int c0 = (tid & 15) * 4;
            const int gr = tid >> 4;
#pragma unroll
            for (int p = 0; p < 4; ++p) {
                const int node = gr*4 + p;
                float a0=0.f, a1=0.f, a2=0.f, a3=0.f;
                if (node < NODES) {
#pragma unroll
                    for (int e = 0; e < EPN; ++e) {
                        const float w = aw[node*EPN + e];
                        const int   s = eS[node*EPN + e];
                        a0 += (s == c0+0) ? w : 0.f;
                        a1 += (s == c0+1) ? w : 0.f;
                        a2 += (s == c0+2) ? w : 0.f;
                        a3 += (s == c0+3) ? w : 0.f;
                    }
                }
                uint2 pv; pv.x = pk2(a0, a1); pv.y = pk2(a2, a3);
                *(uint2*)(Pb + node*XS + c0) = pv;
            }
        }
        __syncthreads();                            // S6

        // aggregation on MFMA + BN register accumulation
        {
            const bf16x8 bk0 = *(const bf16x8*)(Pb + (wv*16 + r16)*XS + 0  + kg*8);
            const bf16x8 bk1 = *(const bf16x8*)(Pb + (wv*16 + r16)*XS + 32 + kg*8);
            const f32x4 zz = {0.f, 0.f, 0.f, 0.f};
            const int d = wv*16 + r16;
#pragma unroll
            for (int ct = 0; ct < 4; ++ct) {
                const bf16x8 ak0 = *(const bf16x8*)(xlt + (ct*16 + r16)*XS + 0  + kg*8);
                const bf16x8 ak1 = *(const bf16x8*)(xlt + (ct*16 + r16)*XS + 32 + kg*8);
                f32x4 d2 = __builtin_amdgcn_mfma_f32_16x16x32_bf16(ak0, bk0, zz, 0, 0, 0);
                d2 = __builtin_amdgcn_mfma_f32_16x16x32_bf16(ak1, bk1, d2, 0, 0, 0);
                if (d < NODES) {
                    const float4 bs = *(const float4*)(bias + ct*16 + kg*4);
                    const float h0 = d2[0]+bs.x, h1 = d2[1]+bs.y;
                    const float h2 = d2[2]+bs.z, h3 = d2[3]+bs.w;
                    uint2 hv; hv.x = pk2(h0, h1); hv.y = pk2(h2, h3);
                    *(uint2*)(hb + (size_t)(nbase + d)*HIDC + ct*16 + kg*4) = hv;
                    bns[ct*4+0] += h0; bnq[ct*4+0] += h0*h0;
                    bns[ct*4+1] += h1; bnq[ct*4+1] += h1*h1;
                    bns[ct*4+2] += h2; bnq[ct*4+2] += h2*h2;
                    bns[ct*4+3] += h3; bnq[ct*4+3] += h3*h3;
                }
            }
        }
    }

    // ---- block-level BN partial reduce -> part[block][128] ----
#pragma unroll
    for (int t = 0; t < 16; ++t) {
        bns[t] += __shfl_xor(bns[t],1); bns[t] += __shfl_xor(bns[t],2);
        bns[t] += __shfl_xor(bns[t],4); bns[t] += __shfl_xor(bns[t],8);
        bnq[t] += __shfl_xor(bnq[t],1); bnq[t] += __shfl_xor(bnq[t],2);
        bnq[t] += __shfl_xor(bnq[t],4); bnq[t] += __shfl_xor(bnq[t],8);
    }
    if (r16 == 0) {
#pragma unroll
        for (int ct = 0; ct < 4; ++ct)
#pragma unroll
            for (int j = 0; j < 4; ++j) {
                redS[wv][ct*16 + kg*4 + j] = bns[ct*4+j];
                redQ[wv][ct*16 + kg*4 + j] = bnq[ct*4+j];
            }
    }
    __syncthreads();
    if (tid < 128) {
        const int sel = tid >> 6, c = tid & 63;
        float s = 0.f;
#pragma unroll
        for (int w = 0; w < 4; ++w) s += sel ? redQ[w][c] : redS[w][c];
        part[(size_t)blockIdx.x*128 + tid] = s;
    }

    cg::this_grid().sync();

    // ================= phase 2: BN fold (block 0) =================
    if (blockIdx.x == 0) {
        float* hred = (float*)R0;               // [2][128]
        float* gs   = (float*)(R0 + 1024);      // [128]
        float* tmp  = (float*)(R0 + 1536);      // [128]
        const int nb = gridDim.x;
        const int ch = tid & 127, hg = tid >> 7;
        float s = 0.f;
        for (int r = hg; r < nb; r += 2) s += part[(size_t)r*128 + ch];
        hred[hg*128 + ch] = s;
        __syncthreads();
        if (tid < 128) gs[tid] = hred[tid] + hred[128 + tid];
        __syncthreads();
        if (tid < HIDC) {
            const float invN = 1.f / (float)NTOT;
            const float mu  = gs[tid] * invN;
            const float var = gs[HIDC + tid] * invN - mu*mu;
            const float sc  = gamma[tid] * rsqrtf(var + 1e-5f);
            const float sh  = beta[tid] - mu * sc;
            fw[tid]        = sc * Wl2[tid];
            fw[HIDC + tid] = sc * Wr2[tid];
            tmp[tid]        = sh * Wl2[tid];
            tmp[HIDC + tid] = sh * Wr2[tid];
        }
        __syncthreads();
        if (tid < 64) {
            float aL2 = tmp[tid], aR2 = tmp[64 + tid];
#pragma unroll
            for (int msk = 1; msk < 64; msk <<= 1) {
                aL2 += __shfl_xor(aL2, msk);
                aR2 += __shfl_xor(aR2, msk);
            }
            if (tid == 0) { fw[128] = aL2 + bl2[0]; fw[129] = aR2 + br2[0]; }
        }
    }

    cg::this_grid().sync();

    // ================= phase 3: GATv2 layer 2 + GELU =================
    float* fwL  = (float*)U1;                   // [130]
    float* xl2s = (float*)(U1 + 520);           // [64]
    float* xr2s = (float*)(U1 + 776);           // [64]
    unsigned short* srcs2 = (unsigned short*)U2;

    if (tid < 130) fwL[tid] = fw[tid];
    const float a2v = att2[0];
    const float b2v = bias2[0];

    for (int g = blockIdx.x; g < NGRAPH; g += gridDim.x) {
        const int nbase = g * NODES;
        const int* eg = esrc + (size_t)nbase * DEG;
        __syncthreads();                        // fwL ready / prior iter reads done
        for (int i = tid; i < NODES*DEG; i += 256)
            srcs2[i] = (unsigned short)(eg[i] - nbase);
        {   // xl2/xr2: quad per node, 16 channels per lane (bf16 h)
            const int node = tid >> 2, sub = tid & 3;
            if (node < NODES) {
                const uint4* hp = (const uint4*)(hb + (size_t)(nbase + node)*HIDC + sub*16);
                const uint4 v0 = hp[0];
                const uint4 v1 = hp[1];
                float al = 0.f, ar = 0.f;
                const int cb = sub*16;
                const unsigned int w8[8] = {v0.x,v0.y,v0.z,v0.w,v1.x,v1.y,v1.z,v1.w};
#pragma unroll
                for (int t = 0; t < 8; ++t) {
                    const float f0 = blo(w8[t]), f1 = bhi(w8[t]);
                    al += f0*fwL[cb+2*t]    + f1*fwL[cb+2*t+1];
                    ar += f0*fwL[64+cb+2*t] + f1*fwL[64+cb+2*t+1];
                }
                al += __shfl_xor(al,1); al += __shfl_xor(al,2);
                ar += __shfl_xor(ar,1); ar += __shfl_xor(ar,2);
                if (sub == 0) { xl2s[node] = al + fwL[128]; xr2s[node] = ar + fwL[129]; }
            }
        }
        __syncthreads();
        {   // attention + aggregation: quad per node, edges 4/4/4/(4+self)
            const int n = tid >> 2, sub = tid & 3;
            if (n < NODES) {
                const float xr = xr2s[n];
                const int jb = sub*4;
                const int s0 = srcs2[n*DEG + jb+0];
                const int s1 = srcs2[n*DEG + jb+1];
                const int s2 = srcs2[n*DEG + jb+2];
                const int s3 = srcs2[n*DEG + jb+3];
                const bool h5 = (sub == 3);
                const float x0 = xl2s[s0], x1 = xl2s[s1];
                const float x2 = xl2s[s2], x3 = xl2s[s3];
                const float x4 = xl2s[n];               // self loop
                const float v0 = lrelu(x0+xr)*a2v;
                const float v1 = lrelu(x1+xr)*a2v;
                const float v2 = lrelu(x2+xr)*a2v;
                const float v3 = lrelu(x3+xr)*a2v;
                const float v4 = h5 ? lrelu(x4+xr)*a2v : -1e30f;
                float m = fmaxf(fmaxf(fmaxf(v0,v1), fmaxf(v2,v3)), v4);
                m = fmaxf(m, __shfl_xor(m,1));
                m = fmaxf(m, __shfl_xor(m,2));
                const float e0 = __expf(v0-m), e1 = __expf(v1-m);
                const float e2 = __expf(v2-m), e3 = __expf(v3-m);
                const float e4 = h5 ? __expf(v4-m) : 0.f;
                float ss = e0+e1+e2+e3+e4;
                float ac = e0*x0 + e1*x1 + e2*x2 + e3*x3 + e4*x4;
                ss += __shfl_xor(ss,1); ss += __shfl_xor(ss,2);
                ac += __shfl_xor(ac,1); ac += __shfl_xor(ac,2);
                if (sub == 0) {
                    const float o = ac/(ss + 1e-16f) + b2v;
                    out[(size_t)g*NODES + n] = 0.5f*o*(1.f + erff(o*0.70710678118654752f));
                }
            }
        }
    }
}

extern "C" void kernel_launch(void* const* d_in, const int* in_sizes, int n_in,
                              void* d_out, int out_size, void* d_ws, size_t ws_size,
                              hipStream_t stream) {
    const float* x     = (const float*)d_in[0];
    const int*   edge  = (const int*)d_in[1];     // [2,E]; src = first E
    const float* Wl1   = (const float*)d_in[2];
    const float* bl1   = (const float*)d_in[3];
    const float* Wr1   = (const float*)d_in[4];
    const float* br1   = (const float*)d_in[5];
    const float* att1  = (const float*)d_in[6];
    const float* bias1 = (const float*)d_in[7];
    const float* gamma = (const float*)d_in[8];
    const float* beta  = (const float*)d_in[9];
    const float* Wl2   = (const float*)d_in[10];
    const float* bl2   = (const float*)d_in[11];
    const float* Wr2   = (const float*)d_in[12];
    const float* br2   = (const float*)d_in[13];
    const float* att2  = (const float*)d_in[14];
    const float* bias2 = (const float*)d_in[15];
    float* outp = (float*)d_out;

    unsigned short* hb = (unsigned short*)d_ws;                  // NTOT*64 bf16
    float* part = (float*)((char*)d_ws + (size_t)NTOT*HIDC*2);   // GRIDB*128 f32 (max)
    float* fw   = part + (size_t)GRIDB*128;                      // 130 f32

    // R10 lesson: a fixed 768-block cooperative grid was rejected by the
    // runtime (not co-resident) and silently no-op'd. Derive the grid from
    // the SAME occupancy calculation the cooperative-launch validator uses.
    int dev = 0;
    hipGetDevice(&dev);
    hipDeviceProp_t prop;
    hipGetDeviceProperties(&prop, dev);
    int maxBpc = 0;
    hipOccupancyMaxActiveBlocksPerMultiprocessor(&maxBpc, (const void*)fused_kernel,
                                                 256, 0);
    long grid = (long)maxBpc * (long)prop.multiProcessorCount;
    if (grid > GRIDB) grid = GRIDB;
    if (grid < 1)     grid = 256;     // paranoia floor

    void* args[] = { (void*)&x, (void*)&edge, (void*)&Wl1, (void*)&bl1,
                     (void*)&Wr1, (void*)&br1, (void*)&att1, (void*)&bias1,
                     (void*)&gamma, (void*)&beta, (void*)&Wl2, (void*)&bl2,
                     (void*)&Wr2, (void*)&br2, (void*)&att2, (void*)&bias2,
                     (void*)&hb, (void*)&part, (void*)&fw, (void*)&outp };
    hipLaunchCooperativeKernel((void*)fused_kernel, dim3((unsigned)grid), dim3(256),
                               args, 0, stream);
}